// Round 13
// baseline (80.386 us; speedup 1.0000x reference)
//
#include <hip/hip_runtime.h>
#include <stdint.h>

#define NROW 16384
#define DDIM 128
#define ROWB 256            // bytes per row of bf16 z

constexpr int NB     = 64;              // cols per j-tile
constexpr int NJT    = NROW / NB;       // 256 j-tiles across the matrix
constexpr int CHUNK  = 8;               // max j-tiles per block
// 128-row strips; strip I has ceil((256-2I)/8) blocks; total = 2112
constexpr int NBLK   = 2112;

typedef __bf16 bf16x8 __attribute__((ext_vector_type(8)));
typedef float  f32x4  __attribute__((ext_vector_type(4)));
typedef int    i32x4  __attribute__((ext_vector_type(4)));

typedef const uint32_t __attribute__((address_space(1)))* gptr_t;
typedef uint32_t __attribute__((address_space(3)))*       lptr_t;

__device__ __forceinline__ unsigned short f2bf(float x) {
  union { float f; uint32_t u; } c; c.f = x;
  uint32_t u = c.u + 0x7fffu + ((c.u >> 16) & 1u);   // RNE
  return (unsigned short)(u >> 16);
}

// S(k) = sum_{x=1..k} ceil(x/4)  (blocks in the last k strips)
__device__ __forceinline__ int Sfun(int k) {
  const int q = k >> 2, r = k & 3;
  return 2 * q * (q + 1) + r * (q + 1);
}

// fp32 -> bf16 with the scale folded in: (1/T) * sqrt(log2(e)),
// so the MFMA accumulator equals a*log2(e), ready for v_exp_f32 (exp2).
__global__ __launch_bounds__(256) void prep_kernel(const float* __restrict__ z,
                                                   unsigned short* __restrict__ zs,
                                                   float* __restrict__ s,
                                                   float* __restrict__ out) {
  const float SC = 12.011224087864498f;  // 10 * sqrt(1.4426950408889634)
  int t = blockIdx.x * 256 + threadIdx.x;
  float4 v = reinterpret_cast<const float4*>(z)[t];
  ushort4 o;
  o.x = f2bf(v.x * SC); o.y = f2bf(v.y * SC);
  o.z = f2bf(v.z * SC); o.w = f2bf(v.w * SC);
  reinterpret_cast<ushort4*>(zs)[t] = o;
  if (t < NROW) s[t] = 0.0f;             // rowsum accumulator (ws is poisoned)
  if (t == 0) out[0] = 9.704060527839234f;   // log(16384); reduce adds to it
}

// Symmetry via 128-row strips (r10 skeleton). Round-13 = T15-static
// software pipeline: each barrier region computes MFMA(tile k) INTERLEAVED
// with exp/accumulate of tile k-1 (two named acc states accA/accB via the
// pair-unrolled loop -> all indexing static, rule #20 safe). r10/r12 had
// exp depending on the SAME region's MFMA (serial: MFMA pipe idle during
// exp, VALU idle during MFMA, all waves lockstep) -- now exp(prev) is
// independent of MFMA(cur) AND its ds_reads, so it fills the lgkm waits
// and the MFMA shadow. JT_blk is always even -> peel tile0, drain last.
// Kept: nibble swizzle both-sides (r10: conflicts->0), depth-1 counted
// vmcnt(4) dbuf (r7/r9), 2 barriers/tile, zero-C MFMA, hoisted addressing.
__global__ __launch_bounds__(256, 2) void gemm_exp_kernel(const unsigned short* __restrict__ zs,
                                                          float* __restrict__ s) {
  __shared__ __align__(16) char smem[2 * NB * ROWB + 4 * CHUNK * 64 * 4]; // 32K dbuf + 8K csm
  float* csm = (float*)(smem + 2 * NB * ROWB);   // [4 waves][CHUNK*64 cols]
  const int tid  = threadIdx.x;
  const int lane = tid & 63;
  const int wid  = tid >> 6;

  // blockIdx.x -> (strip I, chunk c): smallest k with S(k) >= NBLK - bid.
  int I, c;
  {
    const int bid = blockIdx.x;
    const int m = NBLK - bid;
    int k = (int)sqrtf(8.0f * (float)m);
    if (k > 128) k = 128;
    if (k < 1) k = 1;
    while (Sfun(k) < m) ++k;
    while (k > 1 && Sfun(k - 1) >= m) --k;
    I = 128 - k;
    c = bid - (NBLK - Sfun(k));
  }
  const int mI     = NJT - 2 * I;                // j-tiles in this strip (even)
  const int jt0    = 2 * I + CHUNK * c;          // first global j-tile
  const int JT_blk = min(CHUNK, mI - CHUNK * c); // tiles this block runs (even, >=2)

  const int rowBase = I * 128 + wid * 32;        // this wave's 32 rows
  const char* zb = (const char*)zs;
  const int kb = (lane >> 4) << 4;               // 16B chunk within K row

  // ---- hoisted addressing (r12) ----
  const char* rq[4];
  {
    const int r = lane & 15;
#pragma unroll
    for (int ks = 0; ks < 4; ++ks)
      rq[ks] = smem + r * 256 + ((ks * 64 + kb) ^ (r << 4));
  }
  const int dBase = wid * 4096 + lane * 16;
  int sOff[4];
#pragma unroll
  for (int i_ = 0; i_ < 4; ++i_) {
    const int db  = dBase + i_ * 1024;
    const int r_  = db >> 8;
    const int cb_ = db & 0xF0;
    sOff[i_] = (jt0 * NB + r_) * ROWB + (cb_ ^ ((r_ & 15) << 4));
  }

#define STAGE(P)                                                               \
  {                                                                            \
    _Pragma("unroll")                                                          \
    for (int i_ = 0; i_ < 4; ++i_) {                                           \
      __builtin_amdgcn_global_load_lds((gptr_t)(zb + sOff[i_]),                \
          (lptr_t)(smem + (P) + dBase + i_ * 1024), 16, 0, 0);                 \
      sOff[i_] += NB * ROWB;                                                   \
    }                                                                          \
  }

  STAGE(0);   // tile 0 -> buf0

  // A fragments: 16x16x32 A layout row=lane&15, k=(lane>>4)*8+e -> 16B/lane
  bf16x8 afrag[2][4];   // [mf][ks]
  {
    const int r0 = rowBase + (lane & 15);
#pragma unroll
    for (int mf = 0; mf < 2; ++mf)
#pragma unroll
      for (int ks = 0; ks < 4; ++ks) {
        i32x4 raw = *reinterpret_cast<const i32x4*>(
            zb + (size_t)(r0 + mf * 16) * ROWB + ks * 64 + kb);
        afrag[mf][ks] = __builtin_bit_cast(bf16x8, raw);
      }
  }

  STAGE(16384);   // tile 1 -> buf1 (JT_blk >= 2 always)

  f32x4 rsv[2];     // rowsum accumulators
  float cs[4];      // colsum accumulators [nf], flushed per tile
  rsv[0] = (f32x4){0.f, 0.f, 0.f, 0.f};
  rsv[1] = (f32x4){0.f, 0.f, 0.f, 0.f};
#pragma unroll
  for (int nf = 0; nf < 4; ++nf) cs[nf] = 0.0f;
  const f32x4 kZ = {0.f, 0.f, 0.f, 0.f};   // zero-C operand for ks=0 MFMA

  f32x4 accA[2][4], accB[2][4];   // two live tile states (static names)

#define MFMA_TILE(P, ACC)                                                      \
  {                                                                            \
    _Pragma("unroll")                                                          \
    for (int ks = 0; ks < 4; ++ks) {                                           \
      bf16x8 bfr[4];                                                           \
      _Pragma("unroll")                                                        \
      for (int nf = 0; nf < 4; ++nf)                                           \
        bfr[nf] = __builtin_bit_cast(bf16x8,                                   \
            *reinterpret_cast<const i32x4*>(rq[ks] + nf * 4096 + (P)));        \
      _Pragma("unroll")                                                        \
      for (int mf = 0; mf < 2; ++mf)                                           \
        _Pragma("unroll")                                                      \
        for (int nf = 0; nf < 4; ++nf)                                         \
          ACC[mf][nf] = (ks == 0)                                              \
              ? __builtin_amdgcn_mfma_f32_16x16x32_bf16(                       \
                    afrag[mf][0], bfr[nf], kZ, 0, 0, 0)                        \
              : __builtin_amdgcn_mfma_f32_16x16x32_bf16(                       \
                    afrag[mf][ks], bfr[nf], ACC[mf][nf], 0, 0, 0);             \
    }                                                                          \
  }

#define EXP_ACC(ACC)                                                           \
  {                                                                            \
    _Pragma("unroll")                                                          \
    for (int mf = 0; mf < 2; ++mf)                                             \
      _Pragma("unroll")                                                        \
      for (int nf = 0; nf < 4; ++nf) {                                         \
        f32x4 a4 = ACC[mf][nf];                                                \
        f32x4 ev;                                                              \
        ev[0] = __builtin_amdgcn_exp2f(a4[0]);                                 \
        ev[1] = __builtin_amdgcn_exp2f(a4[1]);                                 \
        ev[2] = __builtin_amdgcn_exp2f(a4[2]);                                 \
        ev[3] = __builtin_amdgcn_exp2f(a4[3]);                                 \
        rsv[mf] += ev;                                                         \
        cs[nf] += (ev[0] + ev[1]) + (ev[2] + ev[3]);                           \
      }                                                                        \
  }

#define FLUSH(kk)                                                              \
  {                                                                            \
    _Pragma("unroll")                                                          \
    for (int nf = 0; nf < 4; ++nf) {                                           \
      float v = cs[nf];                                                        \
      v += __shfl_xor(v, 16);                                                  \
      v += __shfl_xor(v, 32);                                                  \
      if (lane < 16) csm[wid * (CHUNK * 64) + (kk) * 64 + nf * 16 + lane] = v; \
      cs[nf] = 0.0f;                                                           \
    }                                                                          \
  }

  // Peeled prologue region: tile 0 (no previous tile to exp).
  asm volatile("s_waitcnt vmcnt(4)" ::: "memory");   // tile0 + afrags landed
  __builtin_amdgcn_s_barrier();
  __builtin_amdgcn_s_setprio(1);
  MFMA_TILE(0, accA);
  __builtin_amdgcn_s_setprio(0);
  __builtin_amdgcn_s_barrier();                      // buf0 free

  // Steady state: each region = MFMA(tile t) interleaved with exp(tile t-1).
#pragma unroll 1
  for (int t = 1; t + 1 < JT_blk; t += 2) {
    STAGE(0);                                        // tile t+1 -> buf0
    asm volatile("s_waitcnt vmcnt(4)" ::: "memory"); // tile t landed
    __builtin_amdgcn_s_barrier();
    __builtin_amdgcn_s_setprio(1);
    MFMA_TILE(16384, accB);                          // tile t
    EXP_ACC(accA);                                   // tile t-1 (independent)
    __builtin_amdgcn_s_setprio(0);
    FLUSH(t - 1);
    __builtin_amdgcn_s_barrier();                    // buf1 free

    if (t + 2 < JT_blk) {
      STAGE(16384);                                  // tile t+2 -> buf1
      asm volatile("s_waitcnt vmcnt(4)" ::: "memory");
    } else {
      asm volatile("s_waitcnt vmcnt(0)" ::: "memory");
    }
    __builtin_amdgcn_s_barrier();
    __builtin_amdgcn_s_setprio(1);
    MFMA_TILE(0, accA);                              // tile t+1
    EXP_ACC(accB);                                   // tile t
    __builtin_amdgcn_s_setprio(0);
    FLUSH(t);
    __builtin_amdgcn_s_barrier();                    // buf0 free
  }

  // Tail: tile JT_blk-1 (odd index -> buf1), then drain the last exp.
  asm volatile("s_waitcnt vmcnt(0)" ::: "memory");
  __builtin_amdgcn_s_barrier();
  __builtin_amdgcn_s_setprio(1);
  MFMA_TILE(16384, accB);                            // tile JT_blk-1
  EXP_ACC(accA);                                     // tile JT_blk-2
  __builtin_amdgcn_s_setprio(0);
  FLUSH(JT_blk - 2);
  __builtin_amdgcn_s_barrier();
  EXP_ACC(accB);                                     // last tile
  FLUSH(JT_blk - 1);
#undef STAGE
#undef MFMA_TILE
#undef EXP_ACC
#undef FLUSH

  // Rowsums: C/D layout col=lane&15, row=(lane>>4)*4+reg. Reduce the 16
  // column-lanes, one atomicAdd per row.
#pragma unroll
  for (int mf = 0; mf < 2; ++mf)
#pragma unroll
    for (int r = 0; r < 4; ++r) {
      float v = rsv[mf][r];
      v += __shfl_xor(v, 1);
      v += __shfl_xor(v, 2);
      v += __shfl_xor(v, 4);
      v += __shfl_xor(v, 8);
      if ((lane & 15) == 0) {
        const int row = rowBase + mf * 16 + ((lane >> 4) << 2) + r;
        atomicAdd(&s[row], v);
      }
    }

  // Colsums: combine the 4 per-wave slabs, one atomic per column. Skip
  // columns inside this strip's diagonal 128-square (computed fully there).
  __syncthreads();   // drain csm ds_writes across waves
  {
    const int colBase0 = jt0 * NB;
    const int diagEnd  = (I + 1) * 128;
    const int ncol     = JT_blk * NB;
#pragma unroll
    for (int k4 = 0; k4 < 2; ++k4) {
      const int idx = k4 * 256 + tid;
      if (idx < ncol) {
        const int col = colBase0 + idx;
        if (col >= diagEnd) {
          float sum = csm[idx] + csm[CHUNK * 64 + idx]
                    + csm[2 * CHUNK * 64 + idx] + csm[3 * CHUNK * 64 + idx];
          atomicAdd(&s[col], sum);
        }
      }
    }
  }
}

// 64 blocks x 256 threads, 1 row each; out[0] pre-set to log N by prep.
// Float-atomic ordering jitter ~1e-7 << 4.4e-2 threshold.
__global__ __launch_bounds__(256) void reduce_kernel(const float* __restrict__ s,
                                                     float* __restrict__ out) {
  const int tid  = threadIdx.x;
  const int lane = tid & 63;
  const int wid  = tid >> 6;
  float v = __log2f(s[blockIdx.x * 256 + tid]);
#pragma unroll
  for (int m = 32; m >= 1; m >>= 1) v += __shfl_xor(v, m);
  __shared__ float ws[4];
  if (lane == 0) ws[wid] = v;
  __syncthreads();
  if (tid == 0) {
    const float t = ws[0] + ws[1] + ws[2] + ws[3];
    // contribution: -(ln2/N) * sum(log2 s_i)
    atomicAdd(out, -4.2307473367321867e-5f * t);  // ln2/16384
  }
}

extern "C" void kernel_launch(void* const* d_in, const int* in_sizes, int n_in,
                              void* d_out, int out_size, void* d_ws, size_t ws_size,
                              hipStream_t stream) {
  const float* z = (const float*)d_in[0];
  unsigned short* zs = (unsigned short*)d_ws;                       // 4 MB bf16
  float* s = (float*)((char*)d_ws + (size_t)NROW * DDIM * 2);       // 64 KB rowsums
  float* out = (float*)d_out;

  prep_kernel<<<dim3(NROW * DDIM / 4 / 256), dim3(256), 0, stream>>>(z, zs, s, out);
  gemm_exp_kernel<<<dim3(NBLK), dim3(256), 0, stream>>>(zs, s);
  reduce_kernel<<<dim3(64), dim3(256), 0, stream>>>(s, out);
}

// Round 14
// 61.876 us; speedup vs baseline: 1.2991x; 1.2991x over previous
//
#include <hip/hip_runtime.h>
#include <stdint.h>

#define NROW 16384
#define DDIM 128
#define ROWB 256            // bytes per row of bf16 z

constexpr int NB     = 64;              // cols per j-tile
constexpr int NJT    = NROW / NB;       // 256 j-tiles across the matrix
constexpr int CHUNK  = 8;               // max j-tiles per block
// 128-row strips; strip I has ceil((256-2I)/8) blocks; total = 2112
constexpr int NBLK   = 2112;

typedef __bf16 bf16x8 __attribute__((ext_vector_type(8)));
typedef float  f32x4  __attribute__((ext_vector_type(4)));
typedef int    i32x4  __attribute__((ext_vector_type(4)));

typedef const uint32_t __attribute__((address_space(1)))* gptr_t;
typedef uint32_t __attribute__((address_space(3)))*       lptr_t;

__device__ __forceinline__ unsigned short f2bf(float x) {
  union { float f; uint32_t u; } c; c.f = x;
  uint32_t u = c.u + 0x7fffu + ((c.u >> 16) & 1u);   // RNE
  return (unsigned short)(u >> 16);
}

// S(k) = sum_{x=1..k} ceil(x/4)  (blocks in the last k strips)
__device__ __forceinline__ int Sfun(int k) {
  const int q = k >> 2, r = k & 3;
  return 2 * q * (q + 1) + r * (q + 1);
}

// fp32 -> bf16 with the scale folded in: (1/T) * sqrt(log2(e)),
// so the MFMA accumulator equals a*log2(e), ready for v_exp_f32 (exp2).
__global__ __launch_bounds__(256) void prep_kernel(const float* __restrict__ z,
                                                   unsigned short* __restrict__ zs,
                                                   float* __restrict__ s,
                                                   float* __restrict__ out) {
  const float SC = 12.011224087864498f;  // 10 * sqrt(1.4426950408889634)
  int t = blockIdx.x * 256 + threadIdx.x;
  float4 v = reinterpret_cast<const float4*>(z)[t];
  ushort4 o;
  o.x = f2bf(v.x * SC); o.y = f2bf(v.y * SC);
  o.z = f2bf(v.z * SC); o.w = f2bf(v.w * SC);
  reinterpret_cast<ushort4*>(zs)[t] = o;
  if (t < NROW) s[t] = 0.0f;             // rowsum accumulator (ws is poisoned)
  if (t == 0) out[0] = 9.704060527839234f;   // log(16384); reduce adds to it
}

// ROUND-14 = CONSOLIDATION. r10's gemm (best measured: 57.9us, VGPR 64,
// occupancy 31.7%, conflicts 0) byte-for-byte + r12's parallel prep/reduce
// epilogue (worth ~3.5us, proven independently). Every structural bet since
// r10 regressed (r11 -11us, r12-gemm -3, r13 -17.5); the winners were only:
// symmetry (r1), register-cut occupancy (r7), full-nibble swizzle + setprio
// (r10), parallel epilogue (r12). This combines all four.
__global__ __launch_bounds__(256, 2) void gemm_exp_kernel(const unsigned short* __restrict__ zs,
                                                          float* __restrict__ s) {
  __shared__ __align__(16) char smem[2 * NB * ROWB + 4 * CHUNK * 64 * 4]; // 32K dbuf + 8K csm
  float* csm = (float*)(smem + 2 * NB * ROWB);   // [4 waves][CHUNK*64 cols]
  const int tid  = threadIdx.x;
  const int lane = tid & 63;
  const int wid  = tid >> 6;

  // blockIdx.x -> (strip I, chunk c): smallest k with S(k) >= NBLK - bid.
  int I, c;
  {
    const int bid = blockIdx.x;
    const int m = NBLK - bid;
    int k = (int)sqrtf(8.0f * (float)m);
    if (k > 128) k = 128;
    if (k < 1) k = 1;
    while (Sfun(k) < m) ++k;
    while (k > 1 && Sfun(k - 1) >= m) --k;
    I = 128 - k;
    c = bid - (NBLK - Sfun(k));
  }
  const int mI     = NJT - 2 * I;                // j-tiles in this strip
  const int jt0    = 2 * I + CHUNK * c;          // first global j-tile
  const int JT_blk = min(CHUNK, mI - CHUNK * c); // tiles this block runs

  const int rowBase = I * 128 + wid * 32;        // this wave's 32 rows
  const char* zb = (const char*)zs;
  const int kb = (lane >> 4) << 4;               // 16B chunk within K row

  // A fragments: 16x16x32 A layout row=lane&15, k=(lane>>4)*8+e -> 16B/lane
  bf16x8 afrag[2][4];   // [mf][ks]
  {
    const int r0 = rowBase + (lane & 15);
#pragma unroll
    for (int mf = 0; mf < 2; ++mf)
#pragma unroll
      for (int ks = 0; ks < 4; ++ks) {
        i32x4 raw = *reinterpret_cast<const i32x4*>(
            zb + (size_t)(r0 + mf * 16) * ROWB + ks * 64 + kb);
        afrag[mf][ks] = __builtin_bit_cast(bf16x8, raw);
      }
  }

  f32x4 rsv[2];     // rowsum accumulators
  float cs[4];      // colsum accumulators [nf], flushed to LDS each j-tile
  rsv[0] = (f32x4){0.f, 0.f, 0.f, 0.f};
  rsv[1] = (f32x4){0.f, 0.f, 0.f, 0.f};
#pragma unroll
  for (int nf = 0; nf < 4; ++nf) cs[nf] = 0.0f;

  // Stage j-tile (jt0+k): linear LDS dest + inverse-nibble-swizzled global
  // source; reads apply the same involution (rule #21).
#define STAGE_B(buf, k)                                                          \
  {                                                                              \
    _Pragma("unroll")                                                            \
    for (int i_ = 0; i_ < 4; ++i_) {                                             \
      const int destByte_ = wid * 4096 + i_ * 1024 + lane * 16;                  \
      const int r_  = destByte_ >> 8;                                            \
      const int cb_ = destByte_ & 0xF0;                                          \
      const int srcByte_ = ((jt0 + (k)) * NB + r_) * ROWB                        \
                           + (cb_ ^ ((r_ & 15) << 4));                           \
      __builtin_amdgcn_global_load_lds((gptr_t)(zb + srcByte_),                  \
          (lptr_t)(smem + (buf) * (NB * ROWB) + destByte_), 16, 0, 0);           \
    }                                                                            \
  }

  STAGE_B(0, 0);

#pragma unroll 1   // KEEP ROLLED: unrolling pipelines iterations and spills
  for (int k = 0; k < JT_blk; ++k) {
    const int cur = k & 1;
    if (k + 1 < JT_blk) {
      STAGE_B(cur ^ 1, k + 1);
      asm volatile("s_waitcnt vmcnt(4)" ::: "memory");  // current tile landed
    } else {
      asm volatile("s_waitcnt vmcnt(0)" ::: "memory");
    }
    __builtin_amdgcn_s_barrier();

    f32x4 acc[2][4];
#pragma unroll
    for (int mf = 0; mf < 2; ++mf)
#pragma unroll
      for (int nf = 0; nf < 4; ++nf) {
        f32x4 zv = {0.f, 0.f, 0.f, 0.f};
        acc[mf][nf] = zv;
      }

    // Compute phase at raised priority: waves of other blocks on this SIMD
    // that are in their stage/flush phase yield issue slots to us.
    __builtin_amdgcn_s_setprio(1);
    const char* bufp = smem + cur * (NB * ROWB);
#pragma unroll
    for (int ks = 0; ks < 4; ++ks) {
      bf16x8 bfrag[4];
#pragma unroll
      for (int nf = 0; nf < 4; ++nf) {
        const int r   = nf * 16 + (lane & 15);
        const int kk  = ks * 64 + kb;
        const int off = r * ROWB + (kk ^ ((r & 15) << 4));
        i32x4 raw = *reinterpret_cast<const i32x4*>(bufp + off);
        bfrag[nf] = __builtin_bit_cast(bf16x8, raw);
      }
#pragma unroll
      for (int mf = 0; mf < 2; ++mf)
#pragma unroll
        for (int nf = 0; nf < 4; ++nf)
          acc[mf][nf] = __builtin_amdgcn_mfma_f32_16x16x32_bf16(
              afrag[mf][ks], bfrag[nf], acc[mf][nf], 0, 0, 0);
    }
    __builtin_amdgcn_s_setprio(0);

    // acc holds a*log2(e) -> exp(a) = exp2(acc); feed row + col accumulators
#pragma unroll
    for (int mf = 0; mf < 2; ++mf)
#pragma unroll
      for (int nf = 0; nf < 4; ++nf) {
        f32x4 a4 = acc[mf][nf];
        f32x4 ev;
        ev[0] = __builtin_amdgcn_exp2f(a4[0]);
        ev[1] = __builtin_amdgcn_exp2f(a4[1]);
        ev[2] = __builtin_amdgcn_exp2f(a4[2]);
        ev[3] = __builtin_amdgcn_exp2f(a4[3]);
        rsv[mf] += ev;
        cs[nf] += (ev[0] + ev[1]) + (ev[2] + ev[3]);
      }

    // Flush colsum partials for this tile into the per-wave LDS slab.
#pragma unroll
    for (int nf = 0; nf < 4; ++nf) {
      float v = cs[nf];
      v += __shfl_xor(v, 16);
      v += __shfl_xor(v, 32);
      if (lane < 16) csm[wid * (CHUNK * 64) + k * 64 + nf * 16 + lane] = v;
      cs[nf] = 0.0f;
    }

    __builtin_amdgcn_s_barrier();   // all waves done reading buf[cur]
  }
#undef STAGE_B

  // Rowsums: C/D layout col=lane&15, row=(lane>>4)*4+reg. Reduce the 16
  // column-lanes, one atomicAdd per row.
#pragma unroll
  for (int mf = 0; mf < 2; ++mf)
#pragma unroll
    for (int r = 0; r < 4; ++r) {
      float v = rsv[mf][r];
      v += __shfl_xor(v, 1);
      v += __shfl_xor(v, 2);
      v += __shfl_xor(v, 4);
      v += __shfl_xor(v, 8);
      if ((lane & 15) == 0) {
        const int row = rowBase + mf * 16 + ((lane >> 4) << 2) + r;
        atomicAdd(&s[row], v);
      }
    }

  // Colsums: combine the 4 per-wave slabs, one atomic per column. Skip
  // columns inside this strip's diagonal 128-square (computed fully there).
  __syncthreads();   // drain csm ds_writes across waves
  {
    const int colBase0 = jt0 * NB;
    const int diagEnd  = (I + 1) * 128;
    const int ncol     = JT_blk * NB;
#pragma unroll
    for (int k4 = 0; k4 < 2; ++k4) {
      const int idx = k4 * 256 + tid;
      if (idx < ncol) {
        const int col = colBase0 + idx;
        if (col >= diagEnd) {
          float sum = csm[idx] + csm[CHUNK * 64 + idx]
                    + csm[2 * CHUNK * 64 + idx] + csm[3 * CHUNK * 64 + idx];
          atomicAdd(&s[col], sum);
        }
      }
    }
  }
}

// 64 blocks x 256 threads, 1 row each; out[0] pre-set to log N by prep.
// Float-atomic ordering jitter ~1e-7 << 4.4e-2 threshold.
__global__ __launch_bounds__(256) void reduce_kernel(const float* __restrict__ s,
                                                     float* __restrict__ out) {
  const int tid  = threadIdx.x;
  const int lane = tid & 63;
  const int wid  = tid >> 6;
  float v = __log2f(s[blockIdx.x * 256 + tid]);
#pragma unroll
  for (int m = 32; m >= 1; m >>= 1) v += __shfl_xor(v, m);
  __shared__ float ws[4];
  if (lane == 0) ws[wid] = v;
  __syncthreads();
  if (tid == 0) {
    const float t = ws[0] + ws[1] + ws[2] + ws[3];
    // contribution: -(ln2/N) * sum(log2 s_i)
    atomicAdd(out, -4.2307473367321867e-5f * t);  // ln2/16384
  }
}

extern "C" void kernel_launch(void* const* d_in, const int* in_sizes, int n_in,
                              void* d_out, int out_size, void* d_ws, size_t ws_size,
                              hipStream_t stream) {
  const float* z = (const float*)d_in[0];
  unsigned short* zs = (unsigned short*)d_ws;                       // 4 MB bf16
  float* s = (float*)((char*)d_ws + (size_t)NROW * DDIM * 2);       // 64 KB rowsums
  float* out = (float*)d_out;

  prep_kernel<<<dim3(NROW * DDIM / 4 / 256), dim3(256), 0, stream>>>(z, zs, s, out);
  gemm_exp_kernel<<<dim3(NBLK), dim3(256), 0, stream>>>(zs, s);
  reduce_kernel<<<dim3(64), dim3(256), 0, stream>>>(s, out);
}